// Round 1
// baseline (662.686 us; speedup 1.0000x reference)
//
#include <hip/hip_runtime.h>
#include <hip/hip_bf16.h>
#include <cstdint>
#include <cstddef>

#define BATCH 8
#define CINC  64
#define HH    128
#define WWW   128
#define COUTC 128
#define KKC   9
#define KDIM  576   // KK*CIN, k = kk*64 + c
#define HWC   (HH*WWW)      // 16384
#define NPX   (BATCH*HWC)   // 131072

typedef float f32x4 __attribute__((ext_vector_type(4)));
typedef short bf16x8 __attribute__((ext_vector_type(8)));

static __device__ __forceinline__ unsigned short f2bf(float f){
    unsigned u = __builtin_bit_cast(unsigned, f);
    u += 0x7fffu + ((u >> 16) & 1u);
    return (unsigned short)(u >> 16);
}
static __device__ __forceinline__ float bf2f(unsigned short h){
    return __builtin_bit_cast(float, ((unsigned)h) << 16);
}

// ---------------- K0: pack weights to bf16, k = kk*64+c, row-major [o][k] ----
__global__ __launch_bounds__(256) void prep_weights(
        const float* __restrict__ off_w, const float* __restrict__ mod_w,
        const float* __restrict__ reg_w,
        unsigned short* __restrict__ Wb, unsigned short* __restrict__ Wc)
{
    int idx = blockIdx.x * 256 + threadIdx.x;
    if (idx < COUTC * KDIM) {
        int o = idx / KDIM, k = idx % KDIM;
        int kk = k >> 6, c = k & 63;
        Wb[idx] = f2bf(reg_w[(o * CINC + c) * KKC + kk]);
    }
    int idx2 = idx - COUTC * KDIM;
    if (idx2 >= 0 && idx2 < 32 * KDIM) {
        int o = idx2 / KDIM, k = idx2 % KDIM;
        int kk = k >> 6, c = k & 63;
        float v = 0.f;
        if (o < 18)      v = off_w[(o * CINC + c) * KKC + kk];      // o = kk*2+d
        else if (o < 27) v = mod_w[((o - 18) * CINC + c) * KKC + kk];
        Wc[idx2] = f2bf(v);
    }
}

// ---------------- K1: 1x1 conv, NCHW f32 -> NHWC bf16 ----------------------
__global__ __launch_bounds__(256) void conv1x1(
        const float* __restrict__ x, const float* __restrict__ pre_w,
        const float* __restrict__ pre_b, unsigned short* __restrict__ xp)
{
    __shared__ float wlds[CINC * CINC];   // [ci][co]
    __shared__ float blds[CINC];
    int tid = threadIdx.x;
    for (int i = tid; i < CINC * CINC; i += 256) {
        int co = i >> 6, ci = i & 63;
        wlds[ci * 64 + co] = pre_w[i];    // pre_w[co][ci][1][1]
    }
    if (tid < CINC) blds[tid] = pre_b[tid];
    __syncthreads();

    int px = blockIdx.x * 256 + tid;
    int b = px >> 14, hw = px & 16383;
    float acc[CINC];
    #pragma unroll
    for (int co = 0; co < CINC; ++co) acc[co] = blds[co];
    for (int ci = 0; ci < CINC; ++ci) {
        float xv = x[(size_t)(b * CINC + ci) * HWC + hw];
        #pragma unroll
        for (int co = 0; co < CINC; ++co) acc[co] += xv * wlds[ci * 64 + co];
    }
    unsigned pk[32];
    #pragma unroll
    for (int j = 0; j < 32; ++j)
        pk[j] = (unsigned)f2bf(acc[2*j]) | ((unsigned)f2bf(acc[2*j+1]) << 16);
    uint4* dst = (uint4*)(xp + (size_t)px * 64);
    #pragma unroll
    for (int q = 0; q < 8; ++q)
        dst[q] = make_uint4(pk[4*q], pk[4*q+1], pk[4*q+2], pk[4*q+3]);
}

// ---------------- K23: fused offset-conv + gather + einsum ------------------
// 2048 blocks x 128 threads (2 waves). Tile = 64 px (one b, one h row, w0..w0+63).
// Phase A: offset/mask 3x3 conv via MFMA (N=32 padded), epilogue -> coords LDS.
// Phase B: per-kk bilinear gather (bf16) -> LDS chunk [64][72], 2 MFMA k-steps.
__global__ __launch_bounds__(128) void dcn_main(
        const unsigned short* __restrict__ xp,
        const unsigned short* __restrict__ Wc,
        const unsigned short* __restrict__ Wb,
        const float* __restrict__ off_b,
        const float* __restrict__ mod_b,
        float* __restrict__ out)
{
    __shared__ uint4 smem4[34816 / 16];
    char* smem = (char*)smem4;
    unsigned short* S2 = (unsigned short*)smem;   // [64][72] bf16 (pitch 144B)
    float* coords = (float*)(smem + 9216);        // [3][9][64] f32 (py, px, m)
    float* epi = (float*)smem;                    // [128][68] f32 (epilogue)

    const int tid  = (int)threadIdx.x;
    const int lane = tid & 63;
    const int wv   = tid >> 6;      // wave id 0..1
    const int l15  = lane & 15;
    const int l4   = lane >> 4;     // 0..3

    int bid = (int)blockIdx.x;
    int bswz = (bid & 7) * 256 + (bid >> 3);      // XCD-contiguous swizzle (2048%8==0)
    const int b  = bswz >> 8;
    const int h  = (bswz >> 1) & 127;
    const int w0 = (bswz & 1) << 6;

    const unsigned short* xpb = xp + (size_t)b * HWC * CINC;

    // ================= Phase A: offset/mask conv =================
    f32x4 accA[2][2];
    #pragma unroll
    for (int i = 0; i < 2; ++i)
        #pragma unroll
        for (int j = 0; j < 2; ++j)
            accA[i][j] = (f32x4){0.f, 0.f, 0.f, 0.f};

    for (int kk = 0; kk < 9; ++kk) {
        int dy = kk / 3 - 1, dx = kk % 3 - 1;
        int y = h + dy;
        #pragma unroll
        for (int it = 0; it < 4; ++it) {
            int id = tid + 128 * it;
            int p = id & 63, g = id >> 6;
            int xc = w0 + p + dx;
            uint4 v = make_uint4(0u, 0u, 0u, 0u);
            if ((unsigned)y < 128u && (unsigned)xc < 128u)
                v = *(const uint4*)(xpb + ((size_t)(y * 128 + xc)) * 64 + g * 8);
            *(uint4*)(smem + p * 144 + g * 16) = v;
        }
        __syncthreads();
        #pragma unroll
        for (int s = 0; s < 2; ++s) {
            bf16x8 a0 = *(const bf16x8*)(smem + (32*wv      + l15) * 144 + 64*s + 16*l4);
            bf16x8 a1 = *(const bf16x8*)(smem + (32*wv + 16 + l15) * 144 + 64*s + 16*l4);
            bf16x8 b0 = __builtin_bit_cast(bf16x8,
                *(const uint4*)(Wc + (size_t)(      l15) * KDIM + kk*64 + 32*s + 8*l4));
            bf16x8 b1 = __builtin_bit_cast(bf16x8,
                *(const uint4*)(Wc + (size_t)(16  + l15) * KDIM + kk*64 + 32*s + 8*l4));
            accA[0][0] = __builtin_amdgcn_mfma_f32_16x16x32_bf16(a0, b0, accA[0][0], 0, 0, 0);
            accA[0][1] = __builtin_amdgcn_mfma_f32_16x16x32_bf16(a0, b1, accA[0][1], 0, 0, 0);
            accA[1][0] = __builtin_amdgcn_mfma_f32_16x16x32_bf16(a1, b0, accA[1][0], 0, 0, 0);
            accA[1][1] = __builtin_amdgcn_mfma_f32_16x16x32_bf16(a1, b1, accA[1][1], 0, 0, 0);
        }
        __syncthreads();
    }
    // epilogue A: D[p][o]  (p = row, o = col) -> coords
    #pragma unroll
    for (int fm = 0; fm < 2; ++fm)
    #pragma unroll
    for (int fn = 0; fn < 2; ++fn)
    #pragma unroll
    for (int r = 0; r < 4; ++r) {
        int p = 32*wv + 16*fm + 4*l4 + r;
        int o = 16*fn + l15;
        float v = accA[fm][fn][r];
        if (o < 18) {
            v += off_b[o];
            int kk = o >> 1;
            if ((o & 1) == 0) coords[      kk*64 + p] = (float)(h - 1 + kk/3) + v;
            else              coords[576 + kk*64 + p] = (float)(w0 + p - 1 + (kk % 3)) + v;
        } else if (o < 27) {
            int kk = o - 18;
            v += mod_b[kk];
            coords[1152 + kk*64 + p] = 2.f / (1.f + __expf(-v));
        }
    }
    __syncthreads();

    // ================= Phase B: gather + einsum =================
    f32x4 accB[4][4];
    #pragma unroll
    for (int i = 0; i < 4; ++i)
        #pragma unroll
        for (int j = 0; j < 4; ++j)
            accB[i][j] = (f32x4){0.f, 0.f, 0.f, 0.f};

    for (int kk = 0; kk < 9; ++kk) {
        #pragma unroll
        for (int it = 0; it < 4; ++it) {
            int id = tid + 128 * it;
            int p = id & 63, g = id >> 6;
            float py = coords[       kk*64 + p];
            float pxx = coords[576  + kk*64 + p];
            float mm  = coords[1152 + kk*64 + p];
            float y0f = floorf(py), x0f = floorf(pxx);
            float wy = py - y0f, wx = pxx - x0f;
            int y0 = (int)y0f, x0 = (int)x0f;
            int y1 = y0 + 1, x1 = x0 + 1;
            int y0c = y0 < 0 ? 0 : (y0 > 127 ? 127 : y0);
            int y1c = y1 < 0 ? 0 : (y1 > 127 ? 127 : y1);
            int x0c = x0 < 0 ? 0 : (x0 > 127 ? 127 : x0);
            int x1c = x1 < 0 ? 0 : (x1 > 127 ? 127 : x1);
            bool yv0 = (unsigned)y0 < 128u, yv1 = (unsigned)y1 < 128u;
            bool xv0 = (unsigned)x0 < 128u, xv1 = (unsigned)x1 < 128u;
            const unsigned short* bb = xpb + g * 8;
            uint4 z = make_uint4(0u, 0u, 0u, 0u);
            uint4 v00 = (yv0 && xv0) ? *(const uint4*)(bb + ((size_t)(y0c*128 + x0c)) * 64) : z;
            uint4 v01 = (yv0 && xv1) ? *(const uint4*)(bb + ((size_t)(y0c*128 + x1c)) * 64) : z;
            uint4 v10 = (yv1 && xv0) ? *(const uint4*)(bb + ((size_t)(y1c*128 + x0c)) * 64) : z;
            uint4 v11 = (yv1 && xv1) ? *(const uint4*)(bb + ((size_t)(y1c*128 + x1c)) * 64) : z;
            const unsigned short* q00 = (const unsigned short*)&v00;
            const unsigned short* q01 = (const unsigned short*)&v01;
            const unsigned short* q10 = (const unsigned short*)&v10;
            const unsigned short* q11 = (const unsigned short*)&v11;
            unsigned pk[4];
            #pragma unroll
            for (int jj = 0; jj < 4; ++jj) {
                float s[2];
                #pragma unroll
                for (int hl = 0; hl < 2; ++hl) {
                    int j = 2*jj + hl;
                    float a00 = bf2f(q00[j]), a01 = bf2f(q01[j]);
                    float a10 = bf2f(q10[j]), a11 = bf2f(q11[j]);
                    float top = a00 + wx * (a01 - a00);
                    float bot = a10 + wx * (a11 - a10);
                    s[hl] = (top + wy * (bot - top)) * mm;
                }
                pk[jj] = (unsigned)f2bf(s[0]) | ((unsigned)f2bf(s[1]) << 16);
            }
            *(uint4*)(smem + p * 144 + g * 16) = make_uint4(pk[0], pk[1], pk[2], pk[3]);
        }
        __syncthreads();
        #pragma unroll
        for (int s = 0; s < 2; ++s) {
            bf16x8 af[4], bfr[4];
            #pragma unroll
            for (int fm = 0; fm < 4; ++fm)
                af[fm] = *(const bf16x8*)(smem + (16*fm + l15) * 144 + 64*s + 16*l4);
            #pragma unroll
            for (int fn = 0; fn < 4; ++fn)
                bfr[fn] = __builtin_bit_cast(bf16x8,
                    *(const uint4*)(Wb + (size_t)(64*wv + 16*fn + l15) * KDIM + kk*64 + 32*s + 8*l4));
            #pragma unroll
            for (int fm = 0; fm < 4; ++fm)
                #pragma unroll
                for (int fn = 0; fn < 4; ++fn)
                    accB[fm][fn] = __builtin_amdgcn_mfma_f32_16x16x32_bf16(
                        af[fm], bfr[fn], accB[fm][fn], 0, 0, 0);
        }
        __syncthreads();
    }

    // epilogue B: acc -> LDS [o][p] -> coalesced 256B-row stores
    #pragma unroll
    for (int fm = 0; fm < 4; ++fm)
    #pragma unroll
    for (int fn = 0; fn < 4; ++fn)
    #pragma unroll
    for (int r = 0; r < 4; ++r) {
        int p = 16*fm + 4*l4 + r;
        int o = 64*wv + 16*fn + l15;
        epi[o * 68 + p] = accB[fm][fn][r];
    }
    __syncthreads();
    float* outb = out + (size_t)b * COUTC * HWC + h * 128 + w0;
    #pragma unroll
    for (int pass = 0; pass < 16; ++pass) {
        int o = (tid >> 4) + 8 * pass;
        int c16 = tid & 15;
        f32x4 v = *(const f32x4*)(epi + o * 68 + c16 * 4);
        *(f32x4*)(outb + (size_t)o * HWC + c16 * 4) = v;
    }
}

extern "C" void kernel_launch(void* const* d_in, const int* in_sizes, int n_in,
                              void* d_out, int out_size, void* d_ws, size_t ws_size,
                              hipStream_t stream)
{
    const float* x     = (const float*)d_in[0];
    const float* pre_w = (const float*)d_in[1];
    const float* pre_b = (const float*)d_in[2];
    const float* off_w = (const float*)d_in[3];
    const float* off_b = (const float*)d_in[4];
    const float* mod_w = (const float*)d_in[5];
    const float* mod_b = (const float*)d_in[6];
    const float* reg_w = (const float*)d_in[7];
    float* out = (float*)d_out;

    unsigned short* xp = (unsigned short*)d_ws;                           // 16,777,216 B
    unsigned short* Wb = (unsigned short*)((char*)d_ws + 16777216);       //    147,456 B
    unsigned short* Wc = (unsigned short*)((char*)d_ws + 16777216 + 147456); // 36,864 B

    prep_weights<<<dim3(360), dim3(256), 0, stream>>>(off_w, mod_w, reg_w, Wb, Wc);
    conv1x1<<<dim3(512), dim3(256), 0, stream>>>(x, pre_w, pre_b, xp);
    dcn_main<<<dim3(2048), dim3(128), 0, stream>>>(xp, Wc, Wb, off_b, mod_b, out);
}

// Round 2
// 457.604 us; speedup vs baseline: 1.4482x; 1.4482x over previous
//
#include <hip/hip_runtime.h>
#include <hip/hip_bf16.h>
#include <cstdint>
#include <cstddef>

#define BATCH 8
#define CINC  64
#define HH    128
#define WWW   128
#define COUTC 128
#define KKC   9
#define KDIM  576   // KK*CIN, k = kk*64 + c
#define HWC   (HH*WWW)      // 16384
#define NPX   (BATCH*HWC)   // 131072

typedef float f32x4 __attribute__((ext_vector_type(4)));
typedef short bf16x8 __attribute__((ext_vector_type(8)));

static __device__ __forceinline__ unsigned short f2bf(float f){
    unsigned u = __builtin_bit_cast(unsigned, f);
    u += 0x7fffu + ((u >> 16) & 1u);
    return (unsigned short)(u >> 16);
}
static __device__ __forceinline__ float bf_lo(unsigned u){
    return __builtin_bit_cast(float, u << 16);
}
static __device__ __forceinline__ float bf_hi(unsigned u){
    return __builtin_bit_cast(float, u & 0xffff0000u);
}

// ---------------- K0: pack weights to bf16, k = kk*64+c, row-major [o][k] ----
__global__ __launch_bounds__(256) void prep_weights(
        const float* __restrict__ off_w, const float* __restrict__ mod_w,
        const float* __restrict__ reg_w,
        unsigned short* __restrict__ Wb, unsigned short* __restrict__ Wc)
{
    int idx = blockIdx.x * 256 + threadIdx.x;
    if (idx < COUTC * KDIM) {
        int o = idx / KDIM, k = idx % KDIM;
        int kk = k >> 6, c = k & 63;
        Wb[idx] = f2bf(reg_w[(o * CINC + c) * KKC + kk]);
    }
    int idx2 = idx - COUTC * KDIM;
    if (idx2 >= 0 && idx2 < 32 * KDIM) {
        int o = idx2 / KDIM, k = idx2 % KDIM;
        int kk = k >> 6, c = k & 63;
        float v = 0.f;
        if (o < 18)      v = off_w[(o * CINC + c) * KKC + kk];      // o = kk*2+d
        else if (o < 27) v = mod_w[((o - 18) * CINC + c) * KKC + kk];
        Wc[idx2] = f2bf(v);
    }
}

// ---------------- K1: 1x1 conv, NCHW f32 -> NHWC bf16 ----------------------
__global__ __launch_bounds__(256) void conv1x1(
        const float* __restrict__ x, const float* __restrict__ pre_w,
        const float* __restrict__ pre_b, unsigned short* __restrict__ xp)
{
    __shared__ float wlds[CINC * CINC];   // [ci][co]
    __shared__ float blds[CINC];
    int tid = threadIdx.x;
    for (int i = tid; i < CINC * CINC; i += 256) {
        int co = i >> 6, ci = i & 63;
        wlds[ci * 64 + co] = pre_w[i];    // pre_w[co][ci][1][1]
    }
    if (tid < CINC) blds[tid] = pre_b[tid];
    __syncthreads();

    int px = blockIdx.x * 256 + tid;
    int b = px >> 14, hw = px & 16383;
    float acc[CINC];
    #pragma unroll
    for (int co = 0; co < CINC; ++co) acc[co] = blds[co];
    for (int ci = 0; ci < CINC; ++ci) {
        float xv = x[(size_t)(b * CINC + ci) * HWC + hw];
        #pragma unroll
        for (int co = 0; co < CINC; ++co) acc[co] += xv * wlds[ci * 64 + co];
    }
    unsigned pk[32];
    #pragma unroll
    for (int j = 0; j < 32; ++j)
        pk[j] = (unsigned)f2bf(acc[2*j]) | ((unsigned)f2bf(acc[2*j+1]) << 16);
    uint4* dst = (uint4*)(xp + (size_t)px * 64);
    #pragma unroll
    for (int q = 0; q < 8; ++q)
        dst[q] = make_uint4(pk[4*q], pk[4*q+1], pk[4*q+2], pk[4*q+3]);
}

// ---------------- K2: offset/mask 3x3 conv -> coords[32][NPX] ---------------
// 1024 blocks x 256 threads (4 waves). Wave = M=16 px tile, N=32, barrier-free
// after one-time Wc staging. coords slots: 2k=py_k, 2k+1=px_k, 18+k=mask_k.
__global__ __launch_bounds__(256) void offset_conv(
        const unsigned short* __restrict__ xp,
        const unsigned short* __restrict__ Wc,
        const float* __restrict__ off_b,
        const float* __restrict__ mod_b,
        float* __restrict__ coords)
{
    __shared__ uint4 WcL[32 * 73];   // pitch 73 uint4 = 584 shorts
    int tid = threadIdx.x;
    for (int j = tid; j < 32 * 72; j += 256) {
        int row = j / 72, c16 = j % 72;
        WcL[row * 73 + c16] = ((const uint4*)Wc)[j];
    }
    __syncthreads();
    const unsigned short* WcS = (const unsigned short*)WcL;

    const int lane = tid & 63;
    const int wv   = tid >> 6;
    const int l15  = lane & 15;
    const int l4   = lane >> 4;
    const int wid  = (int)blockIdx.x * 4 + wv;   // 0..4095

    #pragma unroll 1
    for (int it = 0; it < 2; ++it) {
        int t = wid * 2 + it;                    // 0..8191
        int px0 = t << 4;
        int b = px0 >> 14, hw0 = px0 & 16383;
        int h = hw0 >> 7, x0 = hw0 & 127;
        const unsigned short* xpb = xp + (size_t)b * HWC * CINC;

        f32x4 acc[2];
        acc[0] = (f32x4){0.f,0.f,0.f,0.f};
        acc[1] = (f32x4){0.f,0.f,0.f,0.f};

        #pragma unroll
        for (int kk = 0; kk < 9; ++kk) {
            int y  = h  + kk/3 - 1;
            int xx = x0 + l15 + kk%3 - 1;
            bool val = ((unsigned)y < 128u) && ((unsigned)xx < 128u);
            const uint4* src = (const uint4*)(xpb
                + ((size_t)((y & 127) * 128 + (xx & 127))) * 64 + 8 * l4);
            uint4 z = make_uint4(0u,0u,0u,0u);
            uint4 a0 = val ? src[0] : z;     // ch 8*l4..+7
            uint4 a1 = val ? src[4] : z;     // ch 32+8*l4..+7
            bf16x8 A0 = __builtin_bit_cast(bf16x8, a0);
            bf16x8 A1 = __builtin_bit_cast(bf16x8, a1);
            #pragma unroll
            for (int fn = 0; fn < 2; ++fn) {
                const unsigned short* rw = WcS + (16*fn + l15) * 584 + kk*64 + 8*l4;
                bf16x8 B0 = *(const bf16x8*)(rw);
                bf16x8 B1 = *(const bf16x8*)(rw + 32);
                acc[fn] = __builtin_amdgcn_mfma_f32_16x16x32_bf16(A0, B0, acc[fn], 0,0,0);
                acc[fn] = __builtin_amdgcn_mfma_f32_16x16x32_bf16(A1, B1, acc[fn], 0,0,0);
            }
        }

        #pragma unroll
        for (int fn = 0; fn < 2; ++fn) {
            int o = 16*fn + l15;
            float vals[4];
            #pragma unroll
            for (int r = 0; r < 4; ++r) {
                float v = acc[fn][r];
                if (o < 18) {
                    v += off_b[o];
                    int k = o >> 1;
                    if ((o & 1) == 0) v += (float)(h - 1 + k/3);
                    else              v += (float)(x0 + 4*l4 + r - 1 + (k - (k/3)*3));
                } else if (o < 27) {
                    v = 2.f / (1.f + __expf(-(v + mod_b[o - 18])));
                }
                vals[r] = v;
            }
            if (o < 27)
                *(f32x4*)(coords + (size_t)o * NPX + px0 + 4*l4) =
                    (f32x4){vals[0], vals[1], vals[2], vals[3]};
        }
    }
}

// ---------------- K3: gather + einsum, barrier-free per-wave M=16 N=128 -----
// 256 blocks x 512 threads (8 waves). Wb staged once in LDS (149.5 KB).
// Lane (l15,l4): px = px0+l15, channel chunks {8*l4.., 32+8*l4..} == exact
// MFMA A-frag layout -> gather feeds MFMA with no LDS, no barriers.
__global__ __launch_bounds__(512, 2) void gather_einsum(
        const unsigned short* __restrict__ xp,
        const unsigned short* __restrict__ Wb,
        const float* __restrict__ coords,
        float* __restrict__ out)
{
    __shared__ uint4 WbL[128 * 73];   // 149504 B, pitch 584 shorts
    int tid = threadIdx.x;
    for (int j = tid; j < 128 * 72; j += 512) {
        int row = j / 72, c16 = j % 72;
        WbL[row * 73 + c16] = ((const uint4*)Wb)[j];
    }
    __syncthreads();
    const unsigned short* WbS = (const unsigned short*)WbL;

    const int lane = tid & 63;
    const int wv   = tid >> 6;
    const int l15  = lane & 15;
    const int l4   = lane >> 4;

    #pragma unroll 1
    for (int i = 0; i < 4; ++i) {
        int t = (int)blockIdx.x * 32 + wv * 4 + i;
        int px0 = t << 4;
        int b = px0 >> 14, hw0 = px0 & 16383;
        const unsigned short* xpb = xp + (size_t)b * HWC * CINC;
        int pxl = px0 + l15;

        // coords for this lane's px (all 9 kk)
        float pyv[9], pxv[9], mmv[9];
        #pragma unroll
        for (int kk = 0; kk < 9; ++kk) {
            pyv[kk] = coords[(size_t)(2*kk    ) * NPX + pxl];
            pxv[kk] = coords[(size_t)(2*kk + 1) * NPX + pxl];
            mmv[kk] = coords[(size_t)(18 + kk ) * NPX + pxl];
        }

        f32x4 acc[8];
        #pragma unroll
        for (int fn = 0; fn < 8; ++fn) acc[fn] = (f32x4){0.f,0.f,0.f,0.f};

        uint4 cb[2][8];          // [parity][corner*2+chunk]
        float wyA[2], wxA[2], fv[2][4];

        // issue gather loads for kk (parity p)
        #define ISSUE(kk_, p_) do { \
            float Y = pyv[kk_], X = pxv[kk_]; \
            float yf = floorf(Y), xf = floorf(X); \
            wyA[p_] = Y - yf; wxA[p_] = X - xf; \
            int y0 = (int)yf, x0i = (int)xf; \
            int y1 = y0 + 1, x1 = x0i + 1; \
            bool yv0 = (unsigned)y0 < 128u, yv1 = (unsigned)y1 < 128u; \
            bool xv0 = (unsigned)x0i < 128u, xv1 = (unsigned)x1 < 128u; \
            fv[p_][0] = (yv0 && xv0) ? 1.f : 0.f; \
            fv[p_][1] = (yv0 && xv1) ? 1.f : 0.f; \
            fv[p_][2] = (yv1 && xv0) ? 1.f : 0.f; \
            fv[p_][3] = (yv1 && xv1) ? 1.f : 0.f; \
            int yc0 = y0 < 0 ? 0 : (y0 > 127 ? 127 : y0); \
            int yc1 = y1 < 0 ? 0 : (y1 > 127 ? 127 : y1); \
            int xc0 = x0i < 0 ? 0 : (x0i > 127 ? 127 : x0i); \
            int xc1 = x1 < 0 ? 0 : (x1 > 127 ? 127 : x1); \
            const unsigned short* p00 = xpb + (size_t)(yc0*128 + xc0)*64 + 8*l4; \
            const unsigned short* p01 = xpb + (size_t)(yc0*128 + xc1)*64 + 8*l4; \
            const unsigned short* p10 = xpb + (size_t)(yc1*128 + xc0)*64 + 8*l4; \
            const unsigned short* p11 = xpb + (size_t)(yc1*128 + xc1)*64 + 8*l4; \
            cb[p_][0] = *(const uint4*)(p00);      cb[p_][1] = *(const uint4*)(p00 + 32); \
            cb[p_][2] = *(const uint4*)(p01);      cb[p_][3] = *(const uint4*)(p01 + 32); \
            cb[p_][4] = *(const uint4*)(p10);      cb[p_][5] = *(const uint4*)(p10 + 32); \
            cb[p_][6] = *(const uint4*)(p11);      cb[p_][7] = *(const uint4*)(p11 + 32); \
        } while(0)

        ISSUE(0, 0);

        #pragma unroll
        for (int kk = 0; kk < 9; ++kk) {
            const int p = kk & 1;
            if (kk < 8) {
                const int pn = (kk + 1) & 1;
                ISSUE(kk + 1, pn);
            }
            // weights (validity + modulation folded)
            float m = mmv[kk];
            float oy = wyA[p], ox = wxA[p];
            float u00 = (1.f - oy) * (1.f - ox) * m * fv[p][0];
            float u01 = (1.f - oy) * ox         * m * fv[p][1];
            float u10 = oy * (1.f - ox)         * m * fv[p][2];
            float u11 = oy * ox                 * m * fv[p][3];

            unsigned pk0[4], pk1[4];
            #pragma unroll
            for (int d = 0; d < 4; ++d) {
                unsigned q00, q01, q10, q11;
                // chunk s=0 (even cb), per-dword lerp
                q00 = cb[p][0][d]; q01 = cb[p][2][d]; q10 = cb[p][4][d]; q11 = cb[p][6][d];
                {
                    float slo = bf_lo(q00)*u00 + bf_lo(q01)*u01 + bf_lo(q10)*u10 + bf_lo(q11)*u11;
                    float shi = bf_hi(q00)*u00 + bf_hi(q01)*u01 + bf_hi(q10)*u10 + bf_hi(q11)*u11;
                    pk0[d] = (unsigned)f2bf(slo) | ((unsigned)f2bf(shi) << 16);
                }
                // chunk s=1 (odd cb)
                q00 = cb[p][1][d]; q01 = cb[p][3][d]; q10 = cb[p][5][d]; q11 = cb[p][7][d];
                {
                    float slo = bf_lo(q00)*u00 + bf_lo(q01)*u01 + bf_lo(q10)*u10 + bf_lo(q11)*u11;
                    float shi = bf_hi(q00)*u00 + bf_hi(q01)*u01 + bf_hi(q10)*u10 + bf_hi(q11)*u11;
                    pk1[d] = (unsigned)f2bf(slo) | ((unsigned)f2bf(shi) << 16);
                }
            }
            bf16x8 A0 = __builtin_bit_cast(bf16x8, make_uint4(pk0[0], pk0[1], pk0[2], pk0[3]));
            bf16x8 A1 = __builtin_bit_cast(bf16x8, make_uint4(pk1[0], pk1[1], pk1[2], pk1[3]));

            #pragma unroll
            for (int fn = 0; fn < 8; ++fn) {
                const unsigned short* rw = WbS + (size_t)(16*fn + l15) * 584 + kk*64 + 8*l4;
                bf16x8 B0 = *(const bf16x8*)(rw);
                bf16x8 B1 = *(const bf16x8*)(rw + 32);
                acc[fn] = __builtin_amdgcn_mfma_f32_16x16x32_bf16(A0, B0, acc[fn], 0,0,0);
                acc[fn] = __builtin_amdgcn_mfma_f32_16x16x32_bf16(A1, B1, acc[fn], 0,0,0);
            }
        }
        #undef ISSUE

        float* ob = out + (size_t)b * COUTC * HWC + hw0 + 4*l4;
        #pragma unroll
        for (int fn = 0; fn < 8; ++fn)
            *(f32x4*)(ob + (size_t)(16*fn + l15) * HWC) = acc[fn];
    }
}

extern "C" void kernel_launch(void* const* d_in, const int* in_sizes, int n_in,
                              void* d_out, int out_size, void* d_ws, size_t ws_size,
                              hipStream_t stream)
{
    const float* x     = (const float*)d_in[0];
    const float* pre_w = (const float*)d_in[1];
    const float* pre_b = (const float*)d_in[2];
    const float* off_w = (const float*)d_in[3];
    const float* off_b = (const float*)d_in[4];
    const float* mod_w = (const float*)d_in[5];
    const float* mod_b = (const float*)d_in[6];
    const float* reg_w = (const float*)d_in[7];
    float* out = (float*)d_out;

    unsigned short* xp = (unsigned short*)d_ws;                                 // 16,777,216 B
    unsigned short* Wb = (unsigned short*)((char*)d_ws + 16777216);             //    147,456 B
    unsigned short* Wc = (unsigned short*)((char*)d_ws + 16777216 + 147456);    //     36,864 B
    float* coords = (float*)((char*)d_ws + 16777216 + 147456 + 36864);          // 16,777,216 B

    prep_weights<<<dim3(360),  dim3(256), 0, stream>>>(off_w, mod_w, reg_w, Wb, Wc);
    conv1x1    <<<dim3(512),  dim3(256), 0, stream>>>(x, pre_w, pre_b, xp);
    offset_conv<<<dim3(1024), dim3(256), 0, stream>>>(xp, Wc, off_b, mod_b, coords);
    gather_einsum<<<dim3(256), dim3(512), 0, stream>>>(xp, Wb, coords, out);
}